// Round 1
// baseline (256.232 us; speedup 1.0000x reference)
//
#include <hip/hip_runtime.h>
#include <stdint.h>

#define Bn 4
#define Sn 2048
#define En 1024
#define Hn 16
#define Dn 64

// 0.125 * log2(e) folded into Q at projection time (softmax runs in exp2 domain)
#define QSC 0.18033688011112f

typedef unsigned short u16;
typedef short s16x8 __attribute__((ext_vector_type(8)));
typedef float f32x4 __attribute__((ext_vector_type(4)));

#define MFMA16x16x32 __builtin_amdgcn_mfma_f32_16x16x32_bf16

__device__ __forceinline__ u16 f2bf(float f) {
  union { float f; uint32_t u; } v; v.f = f;
  uint32_t u = v.u;
  u += 0x7fffu + ((u >> 16) & 1u);   // round-to-nearest-even
  return (u16)(u >> 16);
}
__device__ __forceinline__ uint32_t f2u(float f) {
  union { float f; uint32_t u; } v; v.f = f; return v.u;
}

#define AS1 __attribute__((address_space(1)))
#define AS3 __attribute__((address_space(3)))
__device__ __forceinline__ void gload_lds16(const void* g, void* l) {
  __builtin_amdgcn_global_load_lds((const AS1 uint32_t*)g, (AS3 uint32_t*)l, 16, 0, 0);
}

// ---------------- fused prep: cast x + repack Wqkv + repack Wo + pack bias ----
__global__ __launch_bounds__(256) void prep_all(
    const float4* __restrict__ x4, ushort4* __restrict__ xb4,
    const float* __restrict__ Wq, const float* __restrict__ Wk,
    const float* __restrict__ Wv, u16* __restrict__ WallT,
    const float* __restrict__ Wo, u16* __restrict__ WoT,
    const float* __restrict__ bq, const float* __restrict__ bk,
    const float* __restrict__ bv, float* __restrict__ biasA)
{
  __shared__ float t[64][65];
  const int tid = threadIdx.x;
  int blk = blockIdx.x;

  if (blk < 8192) {                     // cast x
    int i = blk * 256 + tid;
    float4 v = x4[i];
    ushort4 o;
    o.x = f2bf(v.x); o.y = f2bf(v.y); o.z = f2bf(v.z); o.w = f2bf(v.w);
    xb4[i] = o;
    return;
  }
  blk -= 8192;
  if (blk < 768) {                      // repack Wq/Wk/Wv
    const int e0 = (blk & 15) * 64;
    const int sh = blk >> 4;            // sec*16 + h
    const int sec = sh >> 4, h = sh & 15;
    const float* W = (sec == 0) ? Wq : (sec == 1) ? Wk : Wv;
    const float* Wh = W + (size_t)h * En * Dn;
    const int d = tid & 63, er = tid >> 6;
#pragma unroll
    for (int ee = 0; ee < 64; ee += 4)
      t[ee + er][d] = Wh[(size_t)(e0 + ee + er) * Dn + d];
    __syncthreads();
    const int dd = tid >> 2, eo = (tid & 3) * 16;
    u16* dst = WallT + (size_t)(sec * 1024 + h * 64 + dd) * En + e0 + eo;
#pragma unroll
    for (int i = 0; i < 16; i += 4) {
      ushort4 o;
      o.x = f2bf(t[eo + i + 0][dd]);
      o.y = f2bf(t[eo + i + 1][dd]);
      o.z = f2bf(t[eo + i + 2][dd]);
      o.w = f2bf(t[eo + i + 3][dd]);
      *(ushort4*)(dst + i) = o;
    }
    return;
  }
  blk -= 768;
  if (blk < 256) {                      // repack Wo
    const int k0 = (blk & 15) * 64;
    const int n0 = (blk >> 4) * 64;
    const int c = tid & 63, r4 = tid >> 6;
#pragma unroll
    for (int rr = 0; rr < 64; rr += 4)
      t[rr + r4][c] = Wo[(size_t)(k0 + rr + r4) * En + n0 + c];
    __syncthreads();
    const int n = tid >> 2, ko = (tid & 3) * 16;
    u16* dst = WoT + (size_t)(n0 + n) * (Hn * Dn) + k0 + ko;
#pragma unroll
    for (int i = 0; i < 16; i += 4) {
      ushort4 o;
      o.x = f2bf(t[ko + i + 0][n]);
      o.y = f2bf(t[ko + i + 1][n]);
      o.z = f2bf(t[ko + i + 2][n]);
      o.w = f2bf(t[ko + i + 3][n]);
      *(ushort4*)(dst + i) = o;
    }
    return;
  }
  blk -= 256;
  int n = blk * 256 + tid;              // bias pack
  if (n < 3 * Hn * Dn) {
    int sec = n >> 10, rr = n & 1023;
    const float* bs = (sec == 0) ? bq : (sec == 1) ? bk : bv;
    biasA[n] = bs[rr];
  }
}

// ---------------- GEMM (128^2, 4-wave) kept for the output projection --------
template<int MODE>
__global__ __launch_bounds__(256) void gemm_bt(
    const u16* __restrict__ A, const u16* __restrict__ Bt,
    const float* __restrict__ bias, int M, int N, int K,
    u16* __restrict__ q_out, u16* __restrict__ k_out, u16* __restrict__ v_out,
    float* __restrict__ f_out)
{
  extern __shared__ __align__(16) u16 smem[];
  // layout: [buf0 A | buf1 A | buf0 B | buf1 B], each 4096 u16

  const int tid  = threadIdx.x;
  const int L    = blockIdx.x;
  const int m0   = (L & 63) * 128;
  const int n0   = (L >> 6) * 128;
  const int w    = tid >> 6;
  const int lane = tid & 63;
  const int quad = lane >> 4;
  const int l15  = lane & 15;
  const int mbase = (w >> 1) * 64;
  const int nbase = (w & 1) * 64;
  const int swz   = (quad ^ ((l15 >> 1) & 3)) * 8;   // swizzled 16B segment for frag reads

  f32x4 acc[4][4];
#pragma unroll
  for (int i = 0; i < 4; ++i)
#pragma unroll
    for (int j = 0; j < 4; ++j)
      acc[i][j] = (f32x4){0.f, 0.f, 0.f, 0.f};

  auto stage = [&](int k0, int bf) {
    u16* lA = smem + bf * 4096;
    u16* lB = smem + 2 * 4096 + bf * 4096;
#pragma unroll
    for (int c = 0; c < 2; ++c) {
      int idx = c * 256 + tid;        // 0..511
      int row = idx >> 2, sl = idx & 3;
      int sg = sl ^ ((row >> 1) & 3); // global 16B segment to fetch
      gload_lds16(A  + (size_t)(m0 + row) * K + k0 + sg * 8, &lA[idx * 8]);
      gload_lds16(Bt + (size_t)(n0 + row) * K + k0 + sg * 8, &lB[idx * 8]);
    }
  };

  stage(0, 0);
  int bf = 0;
  for (int k0 = 0; k0 < K; k0 += 32) {
    __syncthreads();                  // drains stage(k0); issued one compute ago
    if (k0 + 32 < K) stage(k0 + 32, bf ^ 1);
    const u16* lA = smem + bf * 4096;
    const u16* lB = smem + 2 * 4096 + bf * 4096;

    s16x8 af[4], bfr[4];
#pragma unroll
    for (int t = 0; t < 4; ++t) {
      af[t]  = *(const s16x8*)&lA[(mbase + t * 16 + l15) * 32 + swz];
      bfr[t] = *(const s16x8*)&lB[(nbase + t * 16 + l15) * 32 + swz];
    }
#pragma unroll
    for (int mt = 0; mt < 4; ++mt)
#pragma unroll
      for (int nt = 0; nt < 4; ++nt)
        acc[mt][nt] = MFMA16x16x32(af[mt], bfr[nt], acc[mt][nt], 0, 0, 0);
    bf ^= 1;
  }

  if (MODE == 0) {
    // (unused in this build — QKV moved to gemm256_qkv)
  } else {
#pragma unroll
    for (int nt = 0; nt < 4; ++nt) {
      int col = n0 + nbase + nt * 16 + l15;
      float bv = bias[col];
#pragma unroll
      for (int mt = 0; mt < 4; ++mt)
#pragma unroll
        for (int r = 0; r < 4; ++r) {
          int row = m0 + mbase + mt * 16 + quad * 4 + r;
          f_out[(size_t)row * N + col] = acc[mt][nt][r] + bv;
        }
    }
  }
}

// ---------------- QKV GEMM: 256x256 tile, 8 waves, 4-phase/K-tile schedule ----
// Guide §5 8-phase template (T2 swizzle + T3/T4 counted-vmcnt + T5 setprio),
// adapted: BK=64, per K-tile 4 phases of 16 MFMA, raw s_barrier (no implicit
// vmcnt drain), one vmcnt(0) gate per K-tile gating loads issued 3-4 phases
// earlier (latency hidden under MFMA). LDS 128 KiB = 2 bufs x (A 32K + B 32K),
// XOR-swizzled (seg ^= row&7) with pre-swizzled global source (rule 21).
// 8 waves = 2M x 4N, per-wave output 128x64 (8x4 frags), acc = 128 VGPR.
// Grid 384 (= 32 mi x 12 ni), XCD-bijective swizzle (384 % 8 == 0), mi-major
// within an XCD so each XCD keeps a 2 MB A-panel set in its L2.
#define LDA_Q(BASE, QM)                                                        \
  do {                                                                         \
    const u16* p_ = (BASE) + (wm * 128 + (QM) * 64 + l15) * 64;                \
    _Pragma("unroll")                                                          \
    for (int i_ = 0; i_ < 4; ++i_) {                                           \
      af[i_][0] = *(const s16x8*)&p_[i_ * 1024 + sw0];                         \
      af[i_][1] = *(const s16x8*)&p_[i_ * 1024 + sw1];                         \
    }                                                                          \
  } while (0)

#define LDB_Q(BASE, QN, BF)                                                    \
  do {                                                                         \
    const u16* p_ = (BASE) + (wn * 64 + (QN) * 32 + l15) * 64;                 \
    _Pragma("unroll")                                                          \
    for (int j_ = 0; j_ < 2; ++j_) {                                           \
      BF[j_][0] = *(const s16x8*)&p_[j_ * 1024 + sw0];                         \
      BF[j_][1] = *(const s16x8*)&p_[j_ * 1024 + sw1];                         \
    }                                                                          \
  } while (0)

#define PH_MM(QM, QN, BF)                                                      \
  do {                                                                         \
    __builtin_amdgcn_s_setprio(1);                                             \
    _Pragma("unroll")                                                          \
    for (int i_ = 0; i_ < 4; ++i_) {                                           \
      _Pragma("unroll")                                                        \
      for (int j_ = 0; j_ < 2; ++j_) {                                         \
        acc[(QM) * 4 + i_][(QN) * 2 + j_] =                                    \
            MFMA16x16x32(af[i_][0], BF[j_][0],                                 \
                         acc[(QM) * 4 + i_][(QN) * 2 + j_], 0, 0, 0);          \
        acc[(QM) * 4 + i_][(QN) * 2 + j_] =                                    \
            MFMA16x16x32(af[i_][1], BF[j_][1],                                 \
                         acc[(QM) * 4 + i_][(QN) * 2 + j_], 0, 0, 0);          \
      }                                                                        \
    }                                                                          \
    __builtin_amdgcn_s_setprio(0);                                             \
  } while (0)

__global__ __launch_bounds__(512, 2) void gemm256_qkv(
    const u16* __restrict__ A, const u16* __restrict__ Bt,
    const float* __restrict__ bias,
    u16* __restrict__ q_out, u16* __restrict__ k_out, u16* __restrict__ v_out)
{
  extern __shared__ __align__(16) u16 smem[];
  // layout: [A buf0 | A buf1 | B buf0 | B buf1], each 16384 u16 (256 rows x 64)

  const int tid  = threadIdx.x;
  const int L    = blockIdx.x;
  const int g    = (L & 7) * 48 + (L >> 3);   // bijective XCD swizzle (384%8==0)
  const int mi   = g / 12;                    // 0..31  (mi-major per XCD)
  const int ni   = g - mi * 12;               // 0..11
  const int m0   = mi * 256;
  const int n0   = ni * 256;

  const int w    = tid >> 6;
  const int lane = tid & 63;
  const int quad = lane >> 4;
  const int l15  = lane & 15;
  const int wm   = w >> 2;                    // 0..1
  const int wn   = w & 3;                     // 0..3
  const int l7   = l15 & 7;
  const int sw0  = (quad ^ l7) * 8;           // k-seg 0..3 (ks=0), xor row&7
  const int sw1  = ((quad + 4) ^ l7) * 8;     // k-seg 4..7 (ks=1)

  // staging: thread owns 16B chunk (row = tid>>3 + 64c, sl = tid&7);
  // fetches global segment sg = sl ^ (row&7)  (row&7 invariant in c)
  const int sr = tid >> 3, sl = tid & 7;
  const int sg = sl ^ (sr & 7);
  const u16* gA = A  + (size_t)(m0 + sr) * En + sg * 8;
  const u16* gB = Bt + (size_t)(n0 + sr) * En + sg * 8;
  const int lbase = tid * 8;

  f32x4 acc[8][4];
#pragma unroll
  for (int i = 0; i < 8; ++i)
#pragma unroll
    for (int j = 0; j < 4; ++j)
      acc[i][j] = (f32x4){0.f, 0.f, 0.f, 0.f};

  s16x8 af[4][2], bf0[2][2], bf1[2][2];

  auto stageA = [&](int k0, int db) {
    u16* d = smem + db * 16384 + lbase;
#pragma unroll
    for (int c = 0; c < 4; ++c)
      gload_lds16(gA + (size_t)c * 65536 + k0, d + c * 4096);
  };
  auto stageB = [&](int k0, int db) {
    u16* d = smem + 32768 + db * 16384 + lbase;
#pragma unroll
    for (int c = 0; c < 4; ++c)
      gload_lds16(gB + (size_t)c * 65536 + k0, d + c * 4096);
  };

  // prologue: tile 0 fully staged, drained
  stageA(0, 0);
  stageB(0, 0);
  asm volatile("s_waitcnt vmcnt(0)" ::: "memory");
  __builtin_amdgcn_s_barrier();

  for (int t = 0; t < 16; ++t) {
    const int db = t & 1;
    const u16* cA = smem + db * 16384;
    const u16* cB = smem + 32768 + db * 16384;
    const int kn = (t + 1) * 64;

    // ---- phase 0: ds A(half0)+B(half0); issue next-tile A stage ----
    LDA_Q(cA, 0);
    LDB_Q(cB, 0, bf0);
    if (t < 15) stageA(kn, db ^ 1);
    __builtin_amdgcn_s_barrier();
    __builtin_amdgcn_s_waitcnt(0xc07f);      // lgkmcnt(0)
    PH_MM(0, 0, bf0);
    __builtin_amdgcn_s_barrier();

    // ---- phase 1: ds B(half1); issue next-tile B stage ----
    LDB_Q(cB, 1, bf1);
    if (t < 15) stageB(kn, db ^ 1);
    __builtin_amdgcn_s_barrier();
    __builtin_amdgcn_s_waitcnt(0xc07f);
    PH_MM(0, 1, bf1);
    __builtin_amdgcn_s_barrier();

    // ---- phase 2: ds A(half1) ----
    LDA_Q(cA, 1);
    __builtin_amdgcn_s_barrier();
    __builtin_amdgcn_s_waitcnt(0xc07f);
    PH_MM(1, 1, bf1);
    __builtin_amdgcn_s_barrier();

    // ---- phase 3: no ds (bf0 held); gate next tile's staged loads ----
    PH_MM(1, 0, bf0);
    asm volatile("s_waitcnt vmcnt(0)" ::: "memory");
    __builtin_amdgcn_s_barrier();
  }

  const int sec = n0 >> 10;                  // 0:Q 1:K 2:V (block-uniform)
  if (sec < 2) {
    float osc = (sec == 0) ? QSC : 1.0f;
    u16* dst = (sec == 0) ? q_out : k_out;
#pragma unroll
    for (int j = 0; j < 4; ++j) {
      int col = n0 + wn * 64 + j * 16 + l15;
      float bv = bias[col];
      int rr = col & 1023;
      int h = rr >> 6, d = rr & 63;
#pragma unroll
      for (int i = 0; i < 8; ++i)
#pragma unroll
        for (int r = 0; r < 4; ++r) {
          int row = m0 + wm * 128 + i * 16 + quad * 4 + r;
          int b = row >> 11, s = row & 2047;
          dst[(((size_t)b * Hn + h) * Sn + s) * Dn + d] =
              f2bf((acc[i][j][r] + bv) * osc);
        }
    }
  } else {
    // V: transpose 256x256 C-tile through LDS (aliases staging, 128 KiB fit)
    // lC[col][row] with 16B-granule XOR swizzle: granule = (row>>3) ^ (col&31)
    __syncthreads();
    u16* lC = smem;
#pragma unroll
    for (int j = 0; j < 4; ++j) {
      int cl = wn * 64 + j * 16 + l15;
      float bv = bias[n0 + cl];
#pragma unroll
      for (int i = 0; i < 8; ++i) {
        int rowl = wm * 128 + i * 16 + quad * 4;
        ushort4 o;
        o.x = f2bf(acc[i][j][0] + bv);
        o.y = f2bf(acc[i][j][1] + bv);
        o.z = f2bf(acc[i][j][2] + bv);
        o.w = f2bf(acc[i][j][3] + bv);
        *(ushort4*)&lC[cl * 256 + (((rowl >> 3) ^ (cl & 31)) << 3) + (rowl & 7)] = o;
      }
    }
    __syncthreads();
    int c = tid >> 1, hh = tid & 1;
    int col = n0 - 2048 + c;
    int h = col >> 6, d = col & 63;
    int b = m0 >> 11;
    int s0 = (m0 & 2047) + hh * 128;
    uint4* dst = (uint4*)&v_out[(((size_t)b * Hn + h) * Dn + d) * Sn + s0];
#pragma unroll
    for (int q = 0; q < 16; ++q) {
      const uint4* src =
          (const uint4*)&lC[c * 256 + (((hh * 16 + q) ^ (c & 31)) << 3)];
      dst[q] = *src;
    }
  }
}

// ---------------- flash attention v8 ----------------
__global__ __launch_bounds__(256, 4) void flash_attn(
    const u16* __restrict__ Qb, const u16* __restrict__ Kb,
    const u16* __restrict__ Vt, u16* __restrict__ conc)
{
  __shared__ __align__(16) u16 lK[2][64 * 64];   // [buf][kk][d] swizzled
  __shared__ __align__(16) u16 lV[2][64 * 64];   // [buf][d][kk] swizzled
  __shared__ __align__(16) u16 lP[4][16 * 64];   // [wave][q][kk], 16B XOR swizzle

  const int L   = blockIdx.x;
  const int bh  = L & 63;
  const int qt  = ((L >> 6) + (bh >> 2)) & 15;
  const int b   = bh >> 4, h = bh & 15;
  const int tid = threadIdx.x;
  const int w   = tid >> 6;
  const int lane = tid & 63;
  const int quad = lane >> 4;
  const int l15  = lane & 15;
  const int q0   = qt * 128;

  const u16* Qh = Qb + (size_t)bh * Sn * Dn;
  const u16* Kh = Kb + (size_t)bh * Sn * Dn;
  const u16* Vh = Vt + (size_t)bh * Dn * Sn;

  const int Q0m[2] = { q0 + w * 16, q0 + 64 + w * 16 };

  s16x8 aq[2][2];                      // Q fragments (B operand), pre-scaled
#pragma unroll
  for (int m = 0; m < 2; ++m)
#pragma unroll
    for (int c = 0; c < 2; ++c)
      aq[m][c] = *(const s16x8*)&Qh[(size_t)(Q0m[m] + l15) * Dn + c * 32 + quad * 8];

  s16x8 kones;                         // bf16 1.0 x8 (A-operand of l-sum MFMA)
#pragma unroll
  for (int i = 0; i < 8; ++i) kones[i] = (short)0x3F80;

  f32x4 acc[2][4];                     // O^T tiles: row d = dt*16+quad*4+r, col q = l15
#pragma unroll
  for (int m = 0; m < 2; ++m)
#pragma unroll
    for (int i = 0; i < 4; ++i) acc[m][i] = (f32x4){0.f, 0.f, 0.f, 0.f};
  const float NEG_INF = -__builtin_inff();
  float lrow[2] = {0.f, 0.f};

  const int sw0 = (quad ^ (l15 & 7)) * 8;
  const int sw1 = ((quad + 4) ^ (l15 & 7)) * 8;
  const int l7  = l15 & 7;

  const int ntiles = 2 * qt + 2;

  auto stage = [&](int kt) {
    int bufb = kt & 1;
    int kk0 = kt * 64;
#pragma unroll
    for (int c = 0; c < 2; ++c) {
      int idx = c * 256 + tid;         // 0..511
      int row = idx >> 3, sl = idx & 7;
      int sg = sl ^ (row & 7);
      gload_lds16(Kh + (size_t)(kk0 + row) * Dn + sg * 8, &lK[bufb][idx * 8]);
      gload_lds16(Vh + (size_t)row * Sn + kk0 + sg * 8, &lV[bufb][idx * 8]);
    }
  };

  stage(0);
  for (int kt = 0; kt < ntiles; ++kt) {
    const int kk0 = kt * 64;
    __syncthreads();                   // drains stage(kt); issued one compute ago
    if (kt + 1 < ntiles) stage(kt + 1);
    const u16* cK = lK[kt & 1];
    const u16* cV = lV[kt & 1];

#pragma unroll
    for (int m = 0; m < 2; ++m) {
      const int Q0 = Q0m[m];
      if (kk0 >= Q0 + 16) continue;    // sub-tile fully masked (wave-uniform)

      // S^T (pre-scaled, exp2 domain): lane = q-row l15, k = kk0 + ct*16 + quad*4 + r
      f32x4 sc[4];
#pragma unroll
      for (int ct = 0; ct < 4; ++ct) {
        s16x8 bk0 = *(const s16x8*)&cK[(ct * 16 + l15) * 64 + sw0];
        s16x8 bk1 = *(const s16x8*)&cK[(ct * 16 + l15) * 64 + sw1];
        f32x4 z = (f32x4){0.f, 0.f, 0.f, 0.f};
        z = MFMA16x16x32(bk0, aq[m][0], z, 0, 0, 0);
        z = MFMA16x16x32(bk1, aq[m][1], z, 0, 0, 0);
        sc[ct] = z;
      }

      const int qg = Q0 + l15;
      if (kk0 + 63 > Q0) {             // diagonal region: causal mask
#pragma unroll
        for (int ct = 0; ct < 4; ++ct)
#pragma unroll
          for (int r = 0; r < 4; ++r) {
            int kkg = kk0 + ct * 16 + quad * 4 + r;
            sc[ct][r] = (kkg <= qg) ? sc[ct][r] : NEG_INF;
          }
      }

      // P = exp2(sc) directly (shift-invariant softmax; masked -inf -> 0)
#pragma unroll
      for (int ct = 0; ct < 4; ++ct)
#pragma unroll
        for (int r = 0; r < 4; ++r)
          sc[ct][r] = __builtin_amdgcn_exp2f(sc[ct][r]);

      // P^T -> lP (truncation pack via v_perm; 16B XOR swizzle, bank-uniform)
      u16* Pw = &lP[w][0];
#pragma unroll
      for (int ct = 0; ct < 4; ++ct) {
        uint32_t d0 = __builtin_amdgcn_perm(f2u(sc[ct][1]), f2u(sc[ct][0]), 0x07060302);
        uint32_t d1 = __builtin_amdgcn_perm(f2u(sc[ct][3]), f2u(sc[ct][2]), 0x07060302);
        uint2 pk; pk.x = d0; pk.y = d1;
        int seg = (ct * 2 + (quad >> 1)) ^ l7;
        *(uint2*)&Pw[l15 * 64 + seg * 8 + (quad & 1) * 4] = pk;
      }
      __builtin_amdgcn_s_waitcnt(0xc07f);   // lgkmcnt(0)

      s16x8 ap0 = *(const s16x8*)&Pw[l15 * 64 + (quad ^ l7) * 8];
      s16x8 ap1 = *(const s16x8*)&Pw[l15 * 64 + ((quad + 4) ^ l7) * 8];

      // l-sum of (truncated) P via ones-row MFMA: C[i][q] = sum_k P[k][q]
      f32x4 zl = (f32x4){0.f, 0.f, 0.f, 0.f};
      zl = MFMA16x16x32(kones, ap0, zl, 0, 0, 0);
      zl = MFMA16x16x32(kones, ap1, zl, 0, 0, 0);

#pragma unroll
      for (int dt = 0; dt < 4; ++dt) {
        s16x8 bv0 = *(const s16x8*)&cV[(dt * 16 + l15) * 64 + sw0];
        s16x8 bv1 = *(const s16x8*)&cV[(dt * 16 + l15) * 64 + sw1];
        acc[m][dt] = MFMA16x16x32(bv0, ap0, acc[m][dt], 0, 0, 0);
        acc[m][dt] = MFMA16x16x32(bv1, ap1, acc[m][dt], 0, 0, 0);
      }
      lrow[m] += zl[0];
    }
  }

  // epilogue: O = acc^T / l -> conc [B, S, H*D] bf16 (lane l15 = q-row)
#pragma unroll
  for (int m = 0; m < 2; ++m) {
    float inv = 1.0f / lrow[m];
    int qg = Q0m[m] + l15;
#pragma unroll
    for (int dt = 0; dt < 4; ++dt) {
      ushort4 o;
      o.x = f2bf(acc[m][dt][0] * inv);
      o.y = f2bf(acc[m][dt][1] * inv);
      o.z = f2bf(acc[m][dt][2] * inv);
      o.w = f2bf(acc[m][dt][3] * inv);
      *(ushort4*)&conc[((size_t)b * Sn + qg) * (Hn * Dn) + h * Dn + dt * 16 + quad * 4] = o;
    }
  }
}

// ---------------- launch ----------------
extern "C" void kernel_launch(void* const* d_in, const int* in_sizes, int n_in,
                              void* d_out, int out_size, void* d_ws, size_t ws_size,
                              hipStream_t stream)
{
  const float* x  = (const float*)d_in[0];
  const float* Wq = (const float*)d_in[1];
  const float* Wk = (const float*)d_in[2];
  const float* Wv = (const float*)d_in[3];
  const float* bq = (const float*)d_in[4];
  const float* bk = (const float*)d_in[5];
  const float* bv = (const float*)d_in[6];
  const float* Wo = (const float*)d_in[7];
  const float* bo = (const float*)d_in[8];
  float* out = (float*)d_out;

  char* p = (char*)d_ws;
  u16* xb    = (u16*)p; p += (size_t)Bn * Sn * En * sizeof(u16);
  u16* WallT = (u16*)p; p += (size_t)3 * Hn * Dn * En * sizeof(u16);
  u16* WoT   = (u16*)p; p += (size_t)En * Hn * Dn * sizeof(u16);
  float* biasA = (float*)p; p += (size_t)3 * Hn * Dn * sizeof(float);
  u16* Qb    = (u16*)p; p += (size_t)Bn * Hn * Sn * Dn * sizeof(u16);
  u16* Kb    = (u16*)p; p += (size_t)Bn * Hn * Sn * Dn * sizeof(u16);
  u16* Vt    = (u16*)p; p += (size_t)Bn * Hn * Dn * Sn * sizeof(u16);
  u16* conc  = (u16*)p; p += (size_t)Bn * Sn * Hn * Dn * sizeof(u16);

  // fused prep: 8192 cast + 768 qkv-repack + 256 wo-repack + 12 bias
  prep_all<<<9228, 256, 0, stream>>>((const float4*)x, (ushort4*)xb,
                                     Wq, Wk, Wv, WallT, Wo, WoT,
                                     bq, bk, bv, biasA);

  // QKV: [8192,1024] x [1024,3072] -> Q (pre-scaled) / K direct / V^T,
  // 256^2 tiles, 8 waves, 128 KiB LDS, counted-vmcnt phase schedule
  size_t smemq = 4 * 16384 * sizeof(u16);   // 131072 B
  gemm256_qkv<<<32 * 12, 512, smemq, stream>>>(xb, WallT, biasA, Qb, Kb, Vt);

  flash_attn<<<(Sn / 128) * Bn * Hn, 256, 0, stream>>>(Qb, Kb, Vt, conc);

  // out: [8192,1024] x [1024,1024] + bo -> fp32
  size_t smem1 = 4 * 4096 * sizeof(u16);    // 32 KB double-buffered staging
  gemm_bt<1><<<8 * 64, 256, smem1, stream>>>(
      conc, WoT, bo, Bn * Sn, En, Hn * Dn, nullptr, nullptr, nullptr, out);
}